// Round 2
// baseline (152.420 us; speedup 1.0000x reference)
//
#include <hip/hip_runtime.h>

// WaveletDomainLoss: mean |haar_dwt(pred) - haar_dwt(target)|
// DWT is linear => compute haar_dwt(pred - target) on the fly, L1-reduce.
// pred/target: (16, 6, 512, 512) fp32 contiguous. Rows of 512 floats.
// Unit = one float4 column-chunk spanning a row pair => 2 Haar 2x2 blocks.
// Total units = 25165824 / 8 = 3145728 = 2048 blocks * 256 threads * 6 iters.
//
// Single fused kernel: per-block partials to ws, deterministic last-block
// final reduction (fixed summation order => bit-identical every call).

#define NBLOCKS 2048
#define NTHREADS 256
#define W 512
#define N_TOTAL 25165824L        // 16*6*512*512
#define N_UNITS (N_TOTAL / 8)    // 3145728

__global__ __launch_bounds__(NTHREADS) void haar_l1_fused(
    const float* __restrict__ pred,
    const float* __restrict__ tgt,
    float* __restrict__ ws,          // NBLOCKS partials
    unsigned* __restrict__ counter,  // zeroed by memsetAsync before launch
    float* __restrict__ out)
{
    long tid = (long)blockIdx.x * NTHREADS + threadIdx.x;
    long stride = (long)gridDim.x * NTHREADS;
    float acc = 0.f;

    for (long u = tid; u < N_UNITS; u += stride) {
        long rp = u >> 7;            // row-pair index (128 float4 per row)
        long c4 = u & 127;           // float4 column
        long base = rp * (2L * W) + c4 * 4;

        float4 p0 = *(const float4*)(pred + base);
        float4 p1 = *(const float4*)(pred + base + W);
        float4 t0 = *(const float4*)(tgt + base);
        float4 t1 = *(const float4*)(tgt + base + W);

        float a, b, c, d, s1, s2, d1, d2;
        // block 0: cols {x,y}
        a = p0.x - t0.x; b = p0.y - t0.y; c = p1.x - t1.x; d = p1.y - t1.y;
        s1 = a + b; s2 = c + d; d1 = a - b; d2 = c - d;
        acc += fabsf(s1 + s2) + fabsf(s1 - s2) + fabsf(d1 + d2) + fabsf(d1 - d2);
        // block 1: cols {z,w}
        a = p0.z - t0.z; b = p0.w - t0.w; c = p1.z - t1.z; d = p1.w - t1.w;
        s1 = a + b; s2 = c + d; d1 = a - b; d2 = c - d;
        acc += fabsf(s1 + s2) + fabsf(s1 - s2) + fabsf(d1 + d2) + fabsf(d1 - d2);
    }

    // wave (64-lane) reduction
    #pragma unroll
    for (int off = 32; off > 0; off >>= 1)
        acc += __shfl_down(acc, off, 64);

    __shared__ float wsum[NTHREADS / 64];
    __shared__ bool isLast;
    int wave = threadIdx.x >> 6;
    int lane = threadIdx.x & 63;
    if (lane == 0) wsum[wave] = acc;
    __syncthreads();

    if (threadIdx.x == 0) {
        float part = wsum[0] + wsum[1] + wsum[2] + wsum[3];
        // agent-scope release store: visible to the acquire side below
        __hip_atomic_store(&ws[blockIdx.x], part,
                           __ATOMIC_RELEASE, __HIP_MEMORY_SCOPE_AGENT);
        unsigned old = __hip_atomic_fetch_add(counter, 1u,
                           __ATOMIC_ACQ_REL, __HIP_MEMORY_SCOPE_AGENT);
        isLast = (old == (unsigned)(gridDim.x - 1));
    }
    __syncthreads();

    if (isLast) {
        // deterministic: fixed summation order over ws[0..NBLOCKS-1]
        float acc2 = 0.f;
        for (int i = threadIdx.x; i < NBLOCKS; i += NTHREADS)
            acc2 += __hip_atomic_load(&ws[i],
                        __ATOMIC_ACQUIRE, __HIP_MEMORY_SCOPE_AGENT);

        #pragma unroll
        for (int off = 32; off > 0; off >>= 1)
            acc2 += __shfl_down(acc2, off, 64);

        __syncthreads();   // reuse wsum safely
        if (lane == 0) wsum[wave] = acc2;
        __syncthreads();
        if (threadIdx.x == 0) {
            const float scale = 0.5f / (float)N_TOTAL;  // 0.5 from Haar, /N mean
            out[0] = (wsum[0] + wsum[1] + wsum[2] + wsum[3]) * scale;
        }
    }
}

extern "C" void kernel_launch(void* const* d_in, const int* in_sizes, int n_in,
                              void* d_out, int out_size, void* d_ws, size_t ws_size,
                              hipStream_t stream) {
    const float* pred = (const float*)d_in[0];
    const float* tgt  = (const float*)d_in[1];
    float* out = (float*)d_out;
    float* ws  = (float*)d_ws;                      // NBLOCKS floats
    unsigned* counter = (unsigned*)(ws + NBLOCKS);  // 4 bytes after partials

    hipMemsetAsync(counter, 0, sizeof(unsigned), stream);
    haar_l1_fused<<<NBLOCKS, NTHREADS, 0, stream>>>(pred, tgt, ws, counter, out);
}

// Round 3
// 37.134 us; speedup vs baseline: 4.1046x; 4.1046x over previous
//
#include <hip/hip_runtime.h>

// WaveletDomainLoss: mean |haar_dwt(pred) - haar_dwt(target)|
// DWT is linear => compute haar_dwt(pred - target) on the fly, L1-reduce.
// pred/target: (16, 6, 512, 512) fp32 contiguous. Rows of 512 floats.
// Unit = one float4 column-chunk spanning a row pair => 2 Haar 2x2 blocks.
// N_UNITS = 3145728 = 2048 blocks * 256 threads * 6 units/thread (exact).
//
// Grid-stride step in float offset is a compile-time constant:
//   u -> u + 524288 units  ==  base -> base + 4194304 floats
// so we compute base0 once and fully unroll 6 iterations, issuing all 24
// float4 loads before the arithmetic (deep memory-level parallelism).
//
// R2 lesson: NO agent-scope acq/rel atomics (buffer_inv sc1 wiped per-XCD L2,
// 3.5x regression). Plain two-kernel reduction, deterministic order.

#define NBLOCKS 2048
#define NTHREADS 256
#define W 512
#define N_TOTAL 25165824L          // 16*6*512*512
#define ITERS 6
#define STEP_FLOATS 4194304L       // (2048*256 units) >> 7 row-pairs * 1024

__global__ __launch_bounds__(NTHREADS) void haar_l1_partial(
    const float* __restrict__ pred,
    const float* __restrict__ tgt,
    float* __restrict__ ws)
{
    long tid = (long)blockIdx.x * NTHREADS + threadIdx.x;   // < 524288
    long rp = tid >> 7;            // row-pair index (128 float4 per row)
    long c4 = tid & 127;           // float4 column
    long base0 = rp * (2L * W) + c4 * 4;

    float4 p0[ITERS], p1[ITERS], t0[ITERS], t1[ITERS];

    #pragma unroll
    for (int it = 0; it < ITERS; ++it) {
        long base = base0 + (long)it * STEP_FLOATS;
        p0[it] = *(const float4*)(pred + base);
        p1[it] = *(const float4*)(pred + base + W);
        t0[it] = *(const float4*)(tgt + base);
        t1[it] = *(const float4*)(tgt + base + W);
    }

    float acc = 0.f;
    #pragma unroll
    for (int it = 0; it < ITERS; ++it) {
        float a, b, c, d, s1, s2, d1, d2;
        // block 0: cols {x,y}
        a = p0[it].x - t0[it].x; b = p0[it].y - t0[it].y;
        c = p1[it].x - t1[it].x; d = p1[it].y - t1[it].y;
        s1 = a + b; s2 = c + d; d1 = a - b; d2 = c - d;
        acc += fabsf(s1 + s2) + fabsf(s1 - s2) + fabsf(d1 + d2) + fabsf(d1 - d2);
        // block 1: cols {z,w}
        a = p0[it].z - t0[it].z; b = p0[it].w - t0[it].w;
        c = p1[it].z - t1[it].z; d = p1[it].w - t1[it].w;
        s1 = a + b; s2 = c + d; d1 = a - b; d2 = c - d;
        acc += fabsf(s1 + s2) + fabsf(s1 - s2) + fabsf(d1 + d2) + fabsf(d1 - d2);
    }

    // wave (64-lane) reduction
    #pragma unroll
    for (int off = 32; off > 0; off >>= 1)
        acc += __shfl_down(acc, off, 64);

    __shared__ float wsum[NTHREADS / 64];
    int wave = threadIdx.x >> 6;
    int lane = threadIdx.x & 63;
    if (lane == 0) wsum[wave] = acc;
    __syncthreads();
    if (threadIdx.x == 0)
        ws[blockIdx.x] = wsum[0] + wsum[1] + wsum[2] + wsum[3];
}

__global__ __launch_bounds__(NTHREADS) void haar_l1_final(
    const float* __restrict__ ws,
    float* __restrict__ out)
{
    float acc = 0.f;
    #pragma unroll
    for (int i = 0; i < NBLOCKS / NTHREADS; ++i)
        acc += ws[i * NTHREADS + threadIdx.x];

    #pragma unroll
    for (int off = 32; off > 0; off >>= 1)
        acc += __shfl_down(acc, off, 64);

    __shared__ float wsum[NTHREADS / 64];
    int wave = threadIdx.x >> 6;
    int lane = threadIdx.x & 63;
    if (lane == 0) wsum[wave] = acc;
    __syncthreads();
    if (threadIdx.x == 0) {
        // coeff = 0.5*(±a±b±c±d); we summed without the 0.5. mean over N_TOTAL.
        const float scale = 0.5f / (float)N_TOTAL;
        out[0] = (wsum[0] + wsum[1] + wsum[2] + wsum[3]) * scale;
    }
}

extern "C" void kernel_launch(void* const* d_in, const int* in_sizes, int n_in,
                              void* d_out, int out_size, void* d_ws, size_t ws_size,
                              hipStream_t stream) {
    const float* pred = (const float*)d_in[0];
    const float* tgt  = (const float*)d_in[1];
    float* out = (float*)d_out;
    float* ws  = (float*)d_ws;   // needs NBLOCKS floats = 8 KiB

    haar_l1_partial<<<NBLOCKS, NTHREADS, 0, stream>>>(pred, tgt, ws);
    haar_l1_final<<<1, NTHREADS, 0, stream>>>(ws, out);
}